// Round 11
// baseline (31728.711 us; speedup 1.0000x reference)
//
#include <hip/hip_runtime.h>
#include <cstddef>

#define BB 256   // batch
#define TT 4096  // time steps
#define HH 64    // hidden
#define NT 512   // threads: 64 units x 8 K-slices
#define CH 16    // chunk depth (steps)
#define NCH (TT / CH)

// smem float layout (bank-tuned):
//   [8, 2056)    xc: 2 bufs x 16 rows x 64 cols  (base ≡ 8 mod 32)
//   [2064, 3088) hist ring: 16 rows x 64         (base ≡ 16 mod 32)
#define XC0   8
#define HIST0 2064
#define SMEMF 3092

#define LOG2E  1.442695041f
#define LOG2E2 2.885390082f

// produced-chunk counters for layer outputs 0..2 (layer l+1 polls row l).
__device__ int g_flags[3 * BB];

__global__ void zero_flags_kernel() { g_flags[threadIdx.x] = 0; }

__device__ __forceinline__ float dpp_xor1(float x) {  // lane ^= 1 (quad_perm)
    return __int_as_float(__builtin_amdgcn_mov_dpp(__float_as_int(x), 0xB1, 0xF, 0xF, true));
}
__device__ __forceinline__ float dpp_xor2(float x) {  // lane ^= 2 (quad_perm)
    return __int_as_float(__builtin_amdgcn_mov_dpp(__float_as_int(x), 0x4E, 0xF, 0xF, true));
}
__device__ __forceinline__ float swz_xor4(float x) {  // lane ^= 4 (ds_swizzle)
    return __int_as_float(__builtin_amdgcn_ds_swizzle(__float_as_int(x), 0x101F));
}
__device__ __forceinline__ float frcp(float x) { return __builtin_amdgcn_rcpf(x); }

// Raw workgroup barrier: LDS-ordering only (no vmcnt drain).
__device__ __forceinline__ void lds_barrier() {
    asm volatile("s_waitcnt lgkmcnt(0)\n\ts_barrier" ::: "memory");
}

// 4-layer pipelined LSTM. Grid = 1024 blocks: block (l = bid>>8, b = bid&255).
// R10 post-mortem: static instruction count is already minimal (~125/wave/step)
// and real issue utilization is ~50% — the loss is chain latency + barrier
// convoying. Fix: 4 INDEPENDENT barrier domains per CU. waves_per_eu(8) forces
// the <=64-VGPR budget (R9 compiled at 60) so all 4 layer-blocks of a batch
// co-reside: 32 waves/CU = 8 waves/SIMD from 4 domains. Everything else is
// verbatim R9 (two correct runs): chunk-granular acquire/release flags,
// seq in-place, lgkm-only per-step barriers.
__global__ __attribute__((amdgpu_flat_work_group_size(NT, NT), amdgpu_waves_per_eu(8)))
void lstm_pipe(const float* __restrict__ xg,    // x [B][T][6]
               const float* __restrict__ Wih0,  // [256][6]
               const float* __restrict__ WihR,  // [3][256][64]
               const float* __restrict__ Whh4,  // [4][256][64]
               const float* __restrict__ bih4,  // [4][256]
               const float* __restrict__ bhh4,  // [4][256]
               float* __restrict__ seq)         // [T][B][64] in-place
{
    const int bid = blockIdx.x;
    const int l   = bid >> 8;
    const int b   = bid & (BB - 1);
    const bool FIRST = (l == 0);
    const bool LAST  = (l == 3);
    const float* Wih = FIRST ? Wih0 : (WihR + (size_t)(l - 1) * 256 * HH);
    const float* Whh = Whh4 + (size_t)l * 256 * HH;
    const float* bih = bih4 + l * 256;
    const float* bhh = bhh4 + l * 256;
    int* const fin  = &g_flags[(l - 1) * BB + b];  // dereferenced only if l>0
    int* const fout = &g_flags[l * BB + b];        // dereferenced only if l<3

    const int tid = threadIdx.x;
    const int j   = tid >> 3;
    const int e   = tid & 7;
    const int eq  = e & 3;
    const int kb  = e >> 2;
    const bool qb0 = (e & 1) != 0;
    const bool qb1 = (e & 2) != 0;

    __shared__ __align__(16) float smem[SMEMF];

    // ---- weights: 16 named float4 = 64 floats ----
    float4 w00, w01, w02, w03, w10, w11, w12, w13;
    float4 w20, w21, w22, w23, w30, w31, w32, w33;
    {
        const float4 z = make_float4(0.f, 0.f, 0.f, 0.f);
        w00 = z; w01 = z; w02 = z; w03 = z; w10 = z; w11 = z; w12 = z; w13 = z;
        w20 = z; w21 = z; w22 = z; w23 = z; w30 = z; w31 = z; w32 = z; w33 = z;
    }
    if (!FIRST || kb == 0) {
        const float* Wp = kb ? Wih : Whh;
#define LDW(q, KS) { const float4* rp = (const float4*)(Wp + ((q << 6) + j) * HH + eq * 16); \
        float4 v0 = rp[0], v1 = rp[1], v2 = rp[2], v3 = rp[3]; \
        (w##q##0) = make_float4(v0.x*KS, v0.y*KS, v0.z*KS, v0.w*KS); \
        (w##q##1) = make_float4(v1.x*KS, v1.y*KS, v1.z*KS, v1.w*KS); \
        (w##q##2) = make_float4(v2.x*KS, v2.y*KS, v2.z*KS, v2.w*KS); \
        (w##q##3) = make_float4(v3.x*KS, v3.y*KS, v3.z*KS, v3.w*KS); }
        LDW(0, LOG2E) LDW(1, LOG2E) LDW(2, LOG2E2) LDW(3, LOG2E)
#undef LDW
    } else if (e == 4) {  // layer 0, x-slice lane: 6-wide rows zero-padded
#define LDW6(q, KS) { const float* rp = Wih + ((q << 6) + j) * 6; \
        (w##q##0) = make_float4(rp[0]*KS, rp[1]*KS, rp[2]*KS, rp[3]*KS); \
        (w##q##1).x = rp[4]*KS; (w##q##1).y = rp[5]*KS; }
        LDW6(0, LOG2E) LDW6(1, LOG2E) LDW6(2, LOG2E2) LDW6(3, LOG2E)
#undef LDW6
    }

    // per-gate bias * ksc / 8 (8-lane reduce tree sums 8 copies -> full bias)
    const float b0 = (bih[0 * 64 + j] + bhh[0 * 64 + j]) * (LOG2E * 0.125f);
    const float b1 = (bih[1 * 64 + j] + bhh[1 * 64 + j]) * (LOG2E * 0.125f);
    const float b2 = (bih[2 * 64 + j] + bhh[2 * 64 + j]) * (LOG2E2 * 0.125f);
    const float b3 = (bih[3 * 64 + j] + bhh[3 * 64 + j]) * (LOG2E * 0.125f);

    const float sg = (eq == 2) ? 2.f : 1.f;   // outer: tanh = 2*s-1
    const float og = (eq == 2) ? -1.f : 0.f;

    // zero hist; layer 0 also zeros xc (cols >=6 stay 0 forever)
    if (FIRST) { for (int i = tid; i < SMEMF; i += NT) smem[i] = 0.f; }
    else       { for (int i = HIST0 + tid; i < SMEMF; i += NT) smem[i] = 0.f; }
    __syncthreads();

    // ---- wait for producer's chunk 0, then stage it ----
    if (!FIRST) {
        if (tid == 0) {
            while (__hip_atomic_load(fin, __ATOMIC_ACQUIRE, __HIP_MEMORY_SCOPE_AGENT) < 1)
                __builtin_amdgcn_s_sleep(8);
        }
        __syncthreads();
    }

    const int srow = tid >> 5;           // 0..15
    const int sc2  = (tid & 31) << 1;    // even col
    const float* gp = nullptr;
    const float* xp = nullptr;
    if (!FIRST) {
        gp = seq + ((size_t)srow * BB + b) * HH + sc2;
        float2 v = *(const float2*)gp;
        *(float2*)&smem[XC0 + srow * 64 + sc2] = v;
        gp += (size_t)CH * BB * HH;      // -> chunk 1
    } else {
        xp = xg + (size_t)b * TT * 6 + tid * 4;
        if (tid < 24) {
            float4 v = *(const float4*)xp;
            float tmp[4] = {v.x, v.y, v.z, v.w};
#pragma unroll
            for (int m = 0; m < 4; ++m) {
                int idx = tid * 4 + m;
                smem[XC0 + (idx / 6) * 64 + (idx % 6)] = tmp[m];
            }
        }
        xp += 96;
    }
    float* sp = seq + ((size_t)srow * BB + b) * HH + sc2;   // flush ptr
    float c = 0.f;
    __syncthreads();

    float2 pf2 = make_float2(0.f, 0.f);
    float4 pf4 = make_float4(0.f, 0.f, 0.f, 0.f);

    for (int ck = 0; ck < NCH; ++ck) {
        const int buf = ck & 1;
        const float* vb  = kb ? (smem + XC0 + buf * 1024 + eq * 16)
                              : (smem + HIST0 - 64 + eq * 16);
        const float* vb0 = kb ? vb : (smem + HIST0 + 15 * 64 + eq * 16);
        const bool pfv = (ck + 1 < NCH);

        // before prefetching chunk ck+1, ensure producer published it
        if (!FIRST && pfv) {
            if (tid == 0) {
                while (__hip_atomic_load(fin, __ATOMIC_ACQUIRE, __HIP_MEMORY_SCOPE_AGENT) < ck + 2)
                    __builtin_amdgcn_s_sleep(8);
            }
            __syncthreads();
        }

#pragma unroll
        for (int ph = 0; ph < CH; ++ph) {
            if (ph == 0 && pfv) {   // issue next-chunk global loads
                if (!FIRST) pf2 = *(const float2*)gp;
                else if (tid < 24) pf4 = *(const float4*)xp;
            }

            const float4* vp = (const float4*)((ph == 0) ? vb0 : (vb + ph * 64));
            const float4 vv0 = vp[0], vv1 = vp[1], vv2 = vp[2], vv3 = vp[3];

            // gate chains: first ops fold bias/8 (fma) and replace zero-init
#define GATE(q, bq, aq) { \
            float pa = fmaf((w##q##0).x, vv0.x, bq); \
            pa = fmaf((w##q##0).y, vv0.y, pa); \
            pa = fmaf((w##q##0).z, vv0.z, pa); \
            pa = fmaf((w##q##0).w, vv0.w, pa); \
            float pb = (w##q##1).x * vv1.x; \
            pb = fmaf((w##q##1).y, vv1.y, pb); \
            pb = fmaf((w##q##1).z, vv1.z, pb); \
            pb = fmaf((w##q##1).w, vv1.w, pb); \
            pa = fmaf((w##q##2).x, vv2.x, pa); \
            pa = fmaf((w##q##2).y, vv2.y, pa); \
            pa = fmaf((w##q##2).z, vv2.z, pa); \
            pa = fmaf((w##q##2).w, vv2.w, pa); \
            pb = fmaf((w##q##3).x, vv3.x, pb); \
            pb = fmaf((w##q##3).y, vv3.y, pb); \
            pb = fmaf((w##q##3).z, vv3.z, pb); \
            pb = fmaf((w##q##3).w, vv3.w, pb); \
            aq = pa + pb; }
            float a0, a1, a2, a3;
            GATE(0, b0, a0) GATE(1, b1, a1) GATE(2, b2, a2) GATE(3, b3, a3)
#undef GATE

            // reduce-scatter over e: lane ends with gate q = e&3
            const float s0 = dpp_xor1(a0), s1 = dpp_xor1(a1);
            const float s2 = dpp_xor1(a2), s3 = dpp_xor1(a3);
            const float k0 = qb0 ? (a1 + s1) : (a0 + s0);
            const float k2 = qb0 ? (a3 + s3) : (a2 + s2);
            const float u0 = dpp_xor2(k0), u2 = dpp_xor2(k2);
            float g = qb1 ? (k2 + u2) : (k0 + u0);
            g += swz_xor4(g);   // known-good xor4 (ds_swizzle)

            // act: sigm via native exp2 (log2e pre-folded into w/b)
            const float act = fmaf(sg, frcp(1.f + exp2f(-g)), og);

            // gather acts, replicated c/h update
            const float v1 = dpp_xor1(act);
            const float v2 = dpp_xor2(act);
            const float v3 = dpp_xor2(v1);
            const float px = act * v2, py = v1 * v3;
            const float P1 = qb0 ? py : px;   // sigm(i)*tanh(g)
            const float A  = qb0 ? act : v1;
            const float Bx = qb0 ? v2 : v3;
            const float fv = qb1 ? Bx : A;    // sigm(f)
            const float ov = qb1 ? A : Bx;    // sigm(o)

            c = fmaf(fv, c, P1);
            const float tc = fmaf(2.f, frcp(1.f + exp2f(c * -LOG2E2)), -1.f);  // tanh(c)
            const float hn = ov * tc;

            if (e == 0) smem[HIST0 + ph * 64 + j] = hn;   // hist[ph] = h(t)

            if (ph == 8 && pfv) {   // land next-chunk stage
                if (!FIRST) {
                    *(float2*)&smem[XC0 + (1 - buf) * 1024 + srow * 64 + sc2] = pf2;
                } else if (tid < 24) {
                    float tmp[4] = {pf4.x, pf4.y, pf4.z, pf4.w};
#pragma unroll
                    for (int m = 0; m < 4; ++m) {
                        int idx = tid * 4 + m;
                        smem[XC0 + (1 - buf) * 1024 + (idx / 6) * 64 + (idx % 6)] = tmp[m];
                    }
                }
            }

            if (ph < CH - 1) lds_barrier();   // LDS-only sync
            else             __syncthreads(); // chunk boundary
        }

        // flush hist rows 0..15 -> seq rows ck*16..+15, then publish chunk
        if (!LAST) {
            float2 hv = *(const float2*)&smem[HIST0 + srow * 64 + sc2];
            *(float2*)sp = hv;
            __syncthreads();   // drains each thread's stores + protects hist[0]
            if (tid == 0)
                __hip_atomic_store(fout, ck + 1, __ATOMIC_RELEASE, __HIP_MEMORY_SCOPE_AGENT);
        } else if (ck == NCH - 1) {
            if (srow == 15) {
                float2 hv = *(const float2*)&smem[HIST0 + 15 * 64 + sc2];
                *(float2*)sp = hv;
            }
        }
        sp += (size_t)CH * BB * HH;
        if (!FIRST) gp += (size_t)CH * BB * HH;
        else        xp += 96;
    }
}

// out[b] = fc_b + sum_j relu(h[T-1][b][j]) * fc_w[j]
__global__ __launch_bounds__(256)
void fc_kernel(const float* __restrict__ seq, const float* __restrict__ fcw,
               const float* __restrict__ fcb, float* __restrict__ out)
{
    __shared__ float w[HH];
    const int tid = threadIdx.x;
    if (tid < HH) w[tid] = fcw[tid];
    __syncthreads();
    const float* h = &seq[((size_t)(TT - 1) * BB + tid) * HH];
    float s = fcb[0];
#pragma unroll
    for (int jj = 0; jj < HH; ++jj)
        s = fmaf(fmaxf(h[jj], 0.f), w[jj], s);
    out[tid] = s;
}

extern "C" void kernel_launch(void* const* d_in, const int* in_sizes, int n_in,
                              void* d_out, int out_size, void* d_ws, size_t ws_size,
                              hipStream_t stream) {
    const float* x    = (const float*)d_in[0];  // [B][T][6]
    const float* Wih0 = (const float*)d_in[1];  // [256][6]
    const float* WihR = (const float*)d_in[2];  // [3][256][64]
    const float* Whh  = (const float*)d_in[3];  // [4][256][64]
    const float* bih  = (const float*)d_in[4];  // [4][256]
    const float* bhh  = (const float*)d_in[5];  // [4][256]
    const float* fcw  = (const float*)d_in[6];  // [1][64]
    const float* fcb  = (const float*)d_in[7];  // [1]
    float* out = (float*)d_out;
    float* seq = (float*)d_ws;                  // [T][B][64] fp32 = 268 MB

    zero_flags_kernel<<<dim3(1), dim3(3 * BB), 0, stream>>>();
    lstm_pipe<<<dim3(4 * BB), dim3(NT), 0, stream>>>(x, Wih0, WihR, Whh, bih, bhh, seq);
    fc_kernel<<<dim3(1), dim3(256), 0, stream>>>(seq, fcw, fcb, out);
}

// Round 12
// 4469.052 us; speedup vs baseline: 7.0997x; 7.0997x over previous
//
#include <hip/hip_runtime.h>
#include <cstddef>

#define BB 256   // batch
#define TT 4096  // time steps
#define HH 64    // hidden
#define NT 256   // 4 waves; wave w owns units 16w..16w+15 (all 4 gates)
#define CH 8     // chunk depth (steps)
#define NCH (TT / CH)
#define NGB 16   // batch groups of 16
#define LOG2E 1.442695041f

typedef __attribute__((ext_vector_type(8))) short short8;   // 8 bf16 (4 VGPR)
typedef __attribute__((ext_vector_type(4))) short short4v;  // 4 bf16 (2 VGPR)
typedef __attribute__((ext_vector_type(4))) float floatx4;

// produced-chunk counters: consumer (l,gb) polls row l-1.
__device__ int g_flags[3 * NGB];
__global__ void zero_flags_kernel() { g_flags[threadIdx.x] = 0; }

__device__ __forceinline__ floatx4 mfma16(short8 a, short8 b, floatx4 c) {
    return __builtin_amdgcn_mfma_f32_16x16x32_bf16(a, b, c, 0, 0, 0);
}
__device__ __forceinline__ float frcp(float x) { return __builtin_amdgcn_rcpf(x); }
__device__ __forceinline__ void lds_barrier() {
    asm volatile("s_waitcnt lgkmcnt(0)\n\ts_barrier" ::: "memory");
}
// fp32 -> bf16 hi/lo split (trunc; lo captures residual to ~2^-17 rel)
__device__ __forceinline__ void bf16split(float v, short& hi, short& lo) {
    unsigned u  = __float_as_uint(v);
    unsigned hu = u & 0xffff0000u;
    hi = (short)(hu >> 16);
    float r = v - __uint_as_float(hu);
    lo = (short)(__float_as_uint(r) >> 16);
}

// MFMA LSTM: grid = 64 blocks = 4 layers x 16 batch-groups (16 batches each).
// Per step: G[256 gates x 16 batch] = [Whh|Wih](bf16 hi/lo) @ [h|x](bf16 hi/lo),
// 3-term split, K=128, 16 C-tiles of 16x16x32. Wave w owns tiles {w,w+4,w+8,
// w+12} -> lane l, reg r holds i,f,g,o of unit 16w+4*(l>>4)+r, batch l&15:
// c/h update is 100% lane-local. Gates pre-scaled by -log2e (-2log2e for g) so
// sigm = rcp(1+exp2(acc)). h/x live as bf16 hi/lo LDS planes [n][72] whose
// ds_read_b128 IS the B-fragment (lane l: n=l&15, k=8*(l>>4)+i per kstep).
// Layer pipeline: R9's proven chunk-granular acquire/release flags, seq
// in-place fp32.
__global__ __attribute__((amdgpu_flat_work_group_size(NT, NT), amdgpu_waves_per_eu(1)))
void lstm_mfma(const float* __restrict__ xg,    // x [B][T][6]
               const float* __restrict__ Wih0,  // [256][6]
               const float* __restrict__ WihR,  // [3][256][64]
               const float* __restrict__ Whh4,  // [4][256][64]
               const float* __restrict__ bih4,  // [4][256]
               const float* __restrict__ bhh4,  // [4][256]
               float* __restrict__ seq)         // [T][B][64] in-place
{
    const int bid = blockIdx.x;
    const int l   = bid >> 4;
    const int gb  = bid & 15;
    const int b0  = gb << 4;
    const bool FIRST = (l == 0);
    const bool LAST  = (l == 3);
    const float* Wih = FIRST ? Wih0 : (WihR + (size_t)(l - 1) * 256 * HH);
    const float* Whh = Whh4 + (size_t)l * 256 * HH;
    int* const fin  = &g_flags[(l - 1) * NGB + gb];  // deref only if l>0
    int* const fout = &g_flags[l * NGB + gb];        // deref only if l<3

    const int tid = threadIdx.x;
    const int w   = tid >> 6;        // wave 0..3
    const int ln  = tid & 63;
    const int n   = ln & 15;         // batch col (B/C), also A-row for loads
    const int g4  = ln >> 4;         // 0..3
    const int k0  = (w << 4) + (g4 << 2);  // this lane's unit base (4 units)

    // LDS planes (bf16), row width 72 (pad) -> b128 fragment reads conflict-free
    __shared__ __align__(16) unsigned short xhi[2][CH][16][72];
    __shared__ __align__(16) unsigned short xlo[2][CH][16][72];
    __shared__ __align__(16) unsigned short hhi[2][16][72];
    __shared__ __align__(16) unsigned short hlo[2][16][72];

    // ---- weight A-fragments: whi/wlo[tile q][kstep s], row=ln&15, k=8*g4+i ----
    short8 whi[4][4], wlo[4][4];
#pragma unroll
    for (int q = 0; q < 4; ++q) {
        const float sc = (q == 2) ? (-2.f * LOG2E) : (-LOG2E);
        const int gr = (q << 6) + (w << 4) + n;   // gate row of tile q
#pragma unroll
        for (int s = 0; s < 4; ++s) {
            const int kb = s * 32 + g4 * 8;
            float wv[8];
#pragma unroll
            for (int i = 0; i < 8; ++i) {
                const int k = kb + i;
                float v;
                if (k < 64)      v = Whh[gr * 64 + k];
                else if (!FIRST) v = Wih[gr * 64 + (k - 64)];
                else             v = (k - 64 < 6) ? Wih[gr * 6 + (k - 64)] : 0.f;
                wv[i] = v * sc;
            }
            short8 hi, lo;
#pragma unroll
            for (int i = 0; i < 8; ++i) { short a, b2; bf16split(wv[i], a, b2); hi[i] = a; lo[i] = b2; }
            whi[q][s] = hi; wlo[q][s] = lo;
        }
    }
    // bias -> C init (row r of tile q = gate 64q + k0 + r)
    floatx4 bias[4];
#pragma unroll
    for (int q = 0; q < 4; ++q) {
        const float sc = (q == 2) ? (-2.f * LOG2E) : (-LOG2E);
#pragma unroll
        for (int r = 0; r < 4; ++r) {
            const int gr = (q << 6) + k0 + r;
            bias[q][r] = (bih4[l * 256 + gr] + bhh4[l * 256 + gr]) * sc;
        }
    }

    // zero LDS (h(-1)=0; x pads/layer0 cols>=6 stay 0)
    {
        unsigned short* p0 = &xhi[0][0][0][0];
        for (int i = tid; i < 2 * CH * 16 * 72; i += NT) { p0[i] = 0; (&xlo[0][0][0][0])[i] = 0; }
        unsigned short* p1 = &hhi[0][0][0];
        for (int i = tid; i < 2 * 16 * 72; i += NT) { p1[i] = 0; (&hlo[0][0][0])[i] = 0; }
    }
    __syncthreads();

    // staging map (layers>=1): thread -> (tt = tid>>5, sn = (tid>>1)&15, kh)
    const int tt = tid >> 5;
    const int sn = (tid >> 1) & 15;
    const int kh = (tid & 1) * 32;
    // layer0 map: tid<128 -> (ttf = tid>>4, nf = tid&15)
    const int ttf = tid >> 4;
    const int nf  = tid & 15;

    // ---- wait for producer chunk 0, stage it into buf 0 ----
    if (!FIRST) {
        if (tid == 0)
            while (__hip_atomic_load(fin, __ATOMIC_ACQUIRE, __HIP_MEMORY_SCOPE_AGENT) < 1)
                __builtin_amdgcn_s_sleep(8);
        __syncthreads();
        const float* src = seq + ((size_t)(0 * CH + tt) * BB + b0 + sn) * HH + kh;
        floatx4 pv[8];
#pragma unroll
        for (int m = 0; m < 8; ++m) pv[m] = ((const floatx4*)src)[m];
#pragma unroll
        for (int m = 0; m < 4; ++m) {
            short8 hi8, lo8;
#pragma unroll
            for (int i = 0; i < 8; ++i) {
                const float v = (i < 4) ? pv[2 * m][i] : pv[2 * m + 1][i - 4];
                short a, b2; bf16split(v, a, b2); hi8[i] = a; lo8[i] = b2;
            }
            *(short8*)&xhi[0][tt][sn][kh + 8 * m] = hi8;
            *(short8*)&xlo[0][tt][sn][kh + 8 * m] = lo8;
        }
    } else if (tid < 128) {
        const float* sx = xg + ((size_t)(b0 + nf) * TT + ttf) * 6;
#pragma unroll
        for (int i = 0; i < 6; ++i) {
            short a, b2; bf16split(sx[i], a, b2);
            xhi[0][ttf][nf][i] = (unsigned short)a;
            xlo[0][ttf][nf][i] = (unsigned short)b2;
        }
    }
    float c0 = 0.f, c1 = 0.f, c2 = 0.f, c3 = 0.f;
    __syncthreads();

    for (int ck = 0; ck < NCH; ++ck) {
        const int buf = ck & 1;
        const bool pfv = (ck + 1 < NCH);
        if (!FIRST && pfv) {   // producer must have published chunk ck+1
            if (tid == 0)
                while (__hip_atomic_load(fin, __ATOMIC_ACQUIRE, __HIP_MEMORY_SCOPE_AGENT) < ck + 2)
                    __builtin_amdgcn_s_sleep(8);
            __syncthreads();
        }
        floatx4 pv[8];
        float xv[6];

#pragma unroll
        for (int ph = 0; ph < CH; ++ph) {
            const int t = ck * CH + ph;
            if (ph == 0 && pfv) {   // issue next-chunk staging loads
                if (!FIRST) {
                    const float* src = seq + ((size_t)((ck + 1) * CH + tt) * BB + b0 + sn) * HH + kh;
#pragma unroll
                    for (int m = 0; m < 8; ++m) pv[m] = ((const floatx4*)src)[m];
                } else if (tid < 128) {
                    const float* sx = xg + ((size_t)(b0 + nf) * TT + (ck + 1) * CH + ttf) * 6;
#pragma unroll
                    for (int i = 0; i < 6; ++i) xv[i] = sx[i];
                }
            }

            // B fragments straight from LDS (layout == fragment)
            const int hb = (t + 1) & 1;   // h(t-1) lives in buf (t-1)&1
            const short8 bh0 = *(const short8*)&hhi[hb][n][g4 * 8];
            const short8 bh1 = *(const short8*)&hhi[hb][n][32 + g4 * 8];
            const short8 bl0 = *(const short8*)&hlo[hb][n][g4 * 8];
            const short8 bl1 = *(const short8*)&hlo[hb][n][32 + g4 * 8];
            const short8 bx0 = *(const short8*)&xhi[buf][ph][n][g4 * 8];
            const short8 bx1 = *(const short8*)&xhi[buf][ph][n][32 + g4 * 8];
            const short8 by0 = *(const short8*)&xlo[buf][ph][n][g4 * 8];
            const short8 by1 = *(const short8*)&xlo[buf][ph][n][32 + g4 * 8];

            floatx4 a0 = bias[0], a1 = bias[1], a2 = bias[2], a3 = bias[3];
#define TERM(bq0, bq1, bq2, bq3, W) \
            a0 = mfma16(W[0][0], bq0, a0); a1 = mfma16(W[1][0], bq0, a1); \
            a2 = mfma16(W[2][0], bq0, a2); a3 = mfma16(W[3][0], bq0, a3); \
            a0 = mfma16(W[0][1], bq1, a0); a1 = mfma16(W[1][1], bq1, a1); \
            a2 = mfma16(W[2][1], bq1, a2); a3 = mfma16(W[3][1], bq1, a3); \
            a0 = mfma16(W[0][2], bq2, a0); a1 = mfma16(W[1][2], bq2, a1); \
            a2 = mfma16(W[2][2], bq2, a2); a3 = mfma16(W[3][2], bq2, a3); \
            a0 = mfma16(W[0][3], bq3, a0); a1 = mfma16(W[1][3], bq3, a1); \
            a2 = mfma16(W[2][3], bq3, a2); a3 = mfma16(W[3][3], bq3, a3);
            TERM(bh0, bh1, bx0, bx1, whi)   // Whi . Shi
            TERM(bl0, bl1, by0, by1, whi)   // Whi . Slo
            TERM(bh0, bh1, bx0, bx1, wlo)   // Wlo . Shi
#undef TERM

            // lane-local epilogue: 4 units (i,f,g,o all in-register)
            floatx4 hv4;
            short4v h4hi, h4lo;
#define UNIT(r, cr) { \
            const float si = frcp(1.f + exp2f(a0[r])); \
            const float sf = frcp(1.f + exp2f(a1[r])); \
            const float tg = fmaf(2.f, frcp(1.f + exp2f(a2[r])), -1.f); \
            const float so = frcp(1.f + exp2f(a3[r])); \
            cr = fmaf(sf, cr, si * tg); \
            const float tc = fmaf(2.f, frcp(1.f + exp2f(cr * (-2.f * LOG2E))), -1.f); \
            const float hv = so * tc; \
            hv4[r] = hv; \
            short ha, hbs; bf16split(hv, ha, hbs); h4hi[r] = ha; h4lo[r] = hbs; }
            UNIT(0, c0) UNIT(1, c1) UNIT(2, c2) UNIT(3, c3)
#undef UNIT

            // h planes (next step's B) + fp32 h to seq (pipeline medium)
            *(short4v*)&hhi[t & 1][n][k0] = h4hi;
            *(short4v*)&hlo[t & 1][n][k0] = h4lo;
            if (!LAST || t == TT - 1)
                *(floatx4*)(seq + ((size_t)t * BB + b0 + n) * HH + k0) = hv4;

            // land next-chunk staging (convert + plane writes), spread over phs
            if (pfv) {
                if (!FIRST) {
                    if (ph >= 4) {
                        const int m = ph - 4;
                        short8 hi8, lo8;
#pragma unroll
                        for (int i = 0; i < 8; ++i) {
                            const float v = (i < 4) ? pv[2 * m][i] : pv[2 * m + 1][i - 4];
                            short a, b2; bf16split(v, a, b2); hi8[i] = a; lo8[i] = b2;
                        }
                        *(short8*)&xhi[1 - buf][tt][sn][kh + 8 * m] = hi8;
                        *(short8*)&xlo[1 - buf][tt][sn][kh + 8 * m] = lo8;
                    }
                } else if (ph == 2 && tid < 128) {
#pragma unroll
                    for (int i = 0; i < 6; ++i) {
                        short a, b2; bf16split(xv[i], a, b2);
                        xhi[1 - buf][ttf][nf][i] = (unsigned short)a;
                        xlo[1 - buf][ttf][nf][i] = (unsigned short)b2;
                    }
                }
            }

            if (ph < CH - 1) lds_barrier();   // LDS-only sync (stores in flight)
            else             __syncthreads(); // chunk end: drains vm for publish
        }
        if (!LAST && tid == 0)
            __hip_atomic_store(fout, ck + 1, __ATOMIC_RELEASE, __HIP_MEMORY_SCOPE_AGENT);
    }
}

// out[b] = fc_b + sum_j relu(h[T-1][b][j]) * fc_w[j]
__global__ __launch_bounds__(256)
void fc_kernel(const float* __restrict__ seq, const float* __restrict__ fcw,
               const float* __restrict__ fcb, float* __restrict__ out)
{
    __shared__ float w[HH];
    const int tid = threadIdx.x;
    if (tid < HH) w[tid] = fcw[tid];
    __syncthreads();
    const float* h = &seq[((size_t)(TT - 1) * BB + tid) * HH];
    float s = fcb[0];
#pragma unroll
    for (int jj = 0; jj < HH; ++jj)
        s = fmaf(fmaxf(h[jj], 0.f), w[jj], s);
    out[tid] = s;
}

extern "C" void kernel_launch(void* const* d_in, const int* in_sizes, int n_in,
                              void* d_out, int out_size, void* d_ws, size_t ws_size,
                              hipStream_t stream) {
    const float* x    = (const float*)d_in[0];  // [B][T][6]
    const float* Wih0 = (const float*)d_in[1];  // [256][6]
    const float* WihR = (const float*)d_in[2];  // [3][256][64]
    const float* Whh  = (const float*)d_in[3];  // [4][256][64]
    const float* bih  = (const float*)d_in[4];  // [4][256]
    const float* bhh  = (const float*)d_in[5];  // [4][256]
    const float* fcw  = (const float*)d_in[6];  // [1][64]
    const float* fcb  = (const float*)d_in[7];  // [1]
    float* out = (float*)d_out;
    float* seq = (float*)d_ws;                  // [T][B][64] fp32 = 268 MB

    zero_flags_kernel<<<dim3(1), dim3(3 * NGB), 0, stream>>>();
    lstm_mfma<<<dim3(4 * NGB), dim3(NT), 0, stream>>>(x, Wih0, WihR, Whh, bih, bhh, seq);
    fc_kernel<<<dim3(1), dim3(256), 0, stream>>>(seq, fcw, fcb, out);
}